// Round 6
// baseline (235.197 us; speedup 1.0000x reference)
//
#include <hip/hip_runtime.h>

// PCEN: x [32, 256, 4096] fp32. EMA over time per row, then
// out = sqrt(x / (m+eps)^0.98 + 2) - sqrt(2).
//
// Wave-per-row, no barriers, no LDS, coalesced, whole row in registers.
// ROUND 6 KEY CHANGE: an asm memory fence after the 16-load burst.
// Rounds 2/4/5 all compiled to VGPR_Count=32 -- the AMDGPU backend's
// occupancy heuristic register-minimized the kernel by sinking +
// re-materializing the row loads (second read of px[] for the epilogue,
// legal since px is readonly __restrict), producing the same
// load-compute-store convoy (~83us, 2.4 TB/s) regardless of source
// structure. The fence makes that transformation ILLEGAL:
//   - the 16 loads cannot sink below a may-write-memory point;
//   - re-loading px[] below the fence could observe different memory,
//     so the loaded values MUST be kept live in registers.
// Expected ~100 VGPR -> 5 waves/SIMD (20/CU), 16 loads in flight per
// wave (320 KB/CU outstanding), store-only tail with no vmcnt waits.
//
// Scan math (verified passing rounds 0-2,5): per-lane 4-elem local EMA
// (segment coeff A4 = 0.975^4), 6-step Hillis-Steele wave scan with
// coeffs A4^(2^d) and 16-way ILP across sub-chunks, then a serial carry
// chain (coeff A256) fused with the epilogue.

constexpr int T_LEN = 4096;
constexpr int LANES = 64;
constexpr int NSUB  = 16;               // sub-chunks of 256 elems (64 x float4)
constexpr int WAVES_PER_BLK = 4;
constexpr int NTHR  = LANES * WAVES_PER_BLK;

constexpr float EPSF = 1e-6f;
constexpr float SF   = 0.025f;
constexpr float A1F  = 0.975f;

// exact powers of 0.975 via constexpr repeated squaring
constexpr double dA1   = 0.975;
constexpr double dA2   = dA1 * dA1;
constexpr double dA4   = dA2 * dA2;     // per-lane segment coeff (4 steps)
constexpr double dA8   = dA4 * dA4;
constexpr double dA16  = dA8 * dA8;
constexpr double dA32  = dA16 * dA16;
constexpr double dA64  = dA32 * dA32;
constexpr double dA128 = dA64 * dA64;
constexpr double dA256 = dA128 * dA128; // per-sub-chunk coeff (64 lanes x 4)

__global__ __launch_bounds__(NTHR) void pcen_wave_kernel(
    const float* __restrict__ x, float* __restrict__ out, int rows)
{
    const int lane = threadIdx.x & 63;
    const int wave = threadIdx.x >> 6;
    const int row  = blockIdx.x * WAVES_PER_BLK + wave;
    if (row >= rows) return;

    const long long base = (long long)row * T_LEN;
    const float4* __restrict__ px   = (const float4*)(x + base);
    float4* __restrict__       pout = (float4*)(out + base);

    const float cA4   = (float)dA4;
    const float cA8   = (float)dA8;
    const float cA16  = (float)dA16;
    const float cA32  = (float)dA32;
    const float cA64  = (float)dA64;
    const float cA128 = (float)dA128;
    const float cA256 = (float)dA256;

    // lane-constant carry decay: A4^lane (lane's segment starts 4*lane steps in)
    float flane = 1.0f;
    if (lane & 1)  flane *= cA4;
    if (lane & 2)  flane *= cA8;
    if (lane & 4)  flane *= cA16;
    if (lane & 8)  flane *= cA32;
    if (lane & 16) flane *= cA64;
    if (lane & 32) flane *= cA128;

    const float SQRT_D = 1.41421356237309515f;  // sqrt(2.0)

    // ---- phase 1: issue ALL 16 coalesced row loads as one burst ----
    float4 d[NSUB];
#pragma unroll
    for (int s = 0; s < NSUB; ++s) d[s] = px[s * LANES + lane];

    // Fence: loads may not sink below this point, and px[] may not be
    // re-read below it (memory may have changed) -> row stays in VGPRs.
    asm volatile("" ::: "memory");

    // ---- phase 2: per-lane local 4-elem scans (zero init) ----
    float Sv[NSUB];
#pragma unroll
    for (int s = 0; s < NSUB; ++s) {
        float m = SF * d[s].x;
        m = fmaf(A1F, m, SF * d[s].y);
        m = fmaf(A1F, m, SF * d[s].z);
        m = fmaf(A1F, m, SF * d[s].w);
        Sv[s] = m;
    }

    // ---- phase 3: 16 independent wave scans, coeff A4^offset (16-way ILP) ----
#pragma unroll
    for (int s = 0; s < NSUB; ++s) {
        float tt;
        tt = __shfl_up(Sv[s], 1,  64); if (lane >= 1)  Sv[s] = fmaf(cA4,   tt, Sv[s]);
        tt = __shfl_up(Sv[s], 2,  64); if (lane >= 2)  Sv[s] = fmaf(cA8,   tt, Sv[s]);
        tt = __shfl_up(Sv[s], 4,  64); if (lane >= 4)  Sv[s] = fmaf(cA16,  tt, Sv[s]);
        tt = __shfl_up(Sv[s], 8,  64); if (lane >= 8)  Sv[s] = fmaf(cA32,  tt, Sv[s]);
        tt = __shfl_up(Sv[s], 16, 64); if (lane >= 16) Sv[s] = fmaf(cA64,  tt, Sv[s]);
        tt = __shfl_up(Sv[s], 32, 64); if (lane >= 32) Sv[s] = fmaf(cA128, tt, Sv[s]);
    }

    // ---- phase 4: serial carry chain fused with epilogue + stores ----
    // carry chain (16 FMAs) is the only serial part; epilogues are
    // independent given seeds; stores are fire-and-forget (no loads
    // follow, so no vmcnt waits are ever induced by them).
    float carry = 0.0f;
#pragma unroll
    for (int s = 0; s < NSUB; ++s) {
        float excl = __shfl_up(Sv[s], 1, 64);
        if (lane == 0) excl = 0.0f;
        float last = __shfl(Sv[s], 63, 64);

        float m = fmaf(flane, carry, excl);   // EMA just before lane's segment
        carry   = fmaf(cA256, carry, last);   // EMA at end of this sub-chunk

        float4 v = d[s];
        float4 o;
        m = fmaf(A1F, m, SF * v.x);
        o.x = __builtin_amdgcn_sqrtf(
                  fmaf(v.x, __builtin_amdgcn_exp2f(
                      -0.98f * __builtin_amdgcn_logf(m + EPSF)), 2.0f)) - SQRT_D;
        m = fmaf(A1F, m, SF * v.y);
        o.y = __builtin_amdgcn_sqrtf(
                  fmaf(v.y, __builtin_amdgcn_exp2f(
                      -0.98f * __builtin_amdgcn_logf(m + EPSF)), 2.0f)) - SQRT_D;
        m = fmaf(A1F, m, SF * v.z);
        o.z = __builtin_amdgcn_sqrtf(
                  fmaf(v.z, __builtin_amdgcn_exp2f(
                      -0.98f * __builtin_amdgcn_logf(m + EPSF)), 2.0f)) - SQRT_D;
        m = fmaf(A1F, m, SF * v.w);
        o.w = __builtin_amdgcn_sqrtf(
                  fmaf(v.w, __builtin_amdgcn_exp2f(
                      -0.98f * __builtin_amdgcn_logf(m + EPSF)), 2.0f)) - SQRT_D;

        pout[s * LANES + lane] = o;
    }
}

extern "C" void kernel_launch(void* const* d_in, const int* in_sizes, int n_in,
                              void* d_out, int out_size, void* d_ws, size_t ws_size,
                              hipStream_t stream) {
    const float* x = (const float*)d_in[0];
    float* out = (float*)d_out;
    const int rows = in_sizes[0] / T_LEN;  // 32*256 = 8192
    const int blocks = (rows + WAVES_PER_BLK - 1) / WAVES_PER_BLK;
    pcen_wave_kernel<<<dim3(blocks), dim3(NTHR), 0, stream>>>(x, out, rows);
}